// Round 6
// baseline (1105.526 us; speedup 1.0000x reference)
//
#include <hip/hip_runtime.h>
#include <hip/hip_bf16.h>
#include <hip/hip_cooperative_groups.h>

namespace cg = cooperative_groups;

typedef __hip_bfloat16 bf16;
typedef __attribute__((ext_vector_type(8))) short bshort8;
typedef __attribute__((ext_vector_type(4))) float float4v;
typedef __attribute__((ext_vector_type(4))) unsigned short ushort4v;

#define N_NODES 10000
#define N_EDGES 320000
#define IN_DIM  128
#define HID_DIM 256
#define OUT_DIM 128

// ---- d_out layout (fp32 elements) ----
// out_x : floats [0          , 1,280,000)    bytes [0          , 5,120,000)
// out_s : floats [1,280,000  , 101,280,000)  bytes [5,120,000  , 405,120,000)
// out_h : floats [101,280,000, 102,560,000)  bytes [405,120,000, 410,240,000)
//
// Scratch lives inside the out_s byte-region (dead before k_sgemm writes it);
// hs (bf16 staging of h_) lives in the out_h region (overwritten by the final
// h-passthrough memcpy AFTER k_sgemm has consumed it). d_ws deliberately unused.
#define SC_AGGX  5120000ull    // A*x  [10000,128] f32          =  5,120,000 B
#define SC_BUFI  10240000ull   // xw2  [10000,2,128] f32 interleaved = 10,240,000 B
#define SC_ESRC  20480000ull   // 320000 i32 = 1,280,000 B
#define SC_EWT   21760000ull   // 320000 f32 = 1,280,000 B (dinv[src] per CSR slot)
#define SC_CNT   23040000ull   // 10000 i32
#define SC_CUR   23080000ull   // 10000 i32
#define SC_RPTR  23120000ull   // 10001 i32
#define SC_DINV  23160064ull   // 10000 f32 (ends 23,200,064 << 405,120,000)
#define OFF_HS   405120000ull  // 10000x128 bf16 = 2,560,000 B (inside out_h's 5.12 MB)

// ---- cooperative prep: zero -> hist -> (dinv + scan) -> CSR fill, one dispatch.
// 1024 blocks x 256 thr (4 blocks/CU guaranteed resident via launch_bounds(256,4)).
// grid.sync() + threadfence between phases gives device-scope ordering.
__global__ __launch_bounds__(256, 4) void k_prep(
        const int* __restrict__ src, const int* __restrict__ dst,
        int* __restrict__ cnt, int* __restrict__ cur,
        int* __restrict__ rptr, float* __restrict__ dinv,
        int* __restrict__ esrc, float* __restrict__ ewt) {
    cg::grid_group grid = cg::this_grid();
    int tid = blockIdx.x * blockDim.x + threadIdx.x;
    int nthr = gridDim.x * blockDim.x;

    // phase 0: zero counters
    for (int i = tid; i < N_NODES; i += nthr) { cnt[i] = 0; cur[i] = 0; }
    __threadfence();
    grid.sync();

    // phase 1: degree histogram, 4 edges per iter (int4 loads)
    const int4* __restrict__ d4 = (const int4*)dst;
    for (int g = tid; g < N_EDGES / 4; g += nthr) {
        int4 d = d4[g];
        if ((unsigned)d.x < N_NODES) atomicAdd(&cnt[d.x], 1);
        if ((unsigned)d.y < N_NODES) atomicAdd(&cnt[d.y], 1);
        if ((unsigned)d.z < N_NODES) atomicAdd(&cnt[d.z], 1);
        if ((unsigned)d.w < N_NODES) atomicAdd(&cnt[d.w], 1);
    }
    __threadfence();
    grid.sync();

    // phase 2: dinv grid-wide; exclusive scan of cnt in block 0 (256 thr x 40 nodes)
    for (int i = tid; i < N_NODES; i += nthr)
        dinv[i] = rsqrtf((float)(cnt[i] + 1));   // deg includes self-loop
    if (blockIdx.x == 0) {
        __shared__ int sums[256];
        int t = threadIdx.x;
        int s = 0;
        for (int i = 0; i < 40; i++) {
            int n = t * 40 + i;
            if (n < N_NODES) s += cnt[n];
        }
        sums[t] = s;
        __syncthreads();
        for (int off = 1; off < 256; off <<= 1) {
            int v = (t >= off) ? sums[t - off] : 0;
            __syncthreads();
            sums[t] += v;
            __syncthreads();
        }
        int run = (t == 0) ? 0 : sums[t - 1];
        for (int i = 0; i < 40; i++) {
            int n = t * 40 + i;
            if (n < N_NODES) { rptr[n] = run; run += cnt[n]; }
        }
        if (t == 0) rptr[N_NODES] = N_EDGES;
    }
    __threadfence();
    grid.sync();

    // phase 3: CSR fill + per-slot weight ewt = dinv[src], 4 edges per iter
    const int4* __restrict__ s4 = (const int4*)src;
    for (int g = tid; g < N_EDGES / 4; g += nthr) {
        int4 sv = s4[g];
        int4 dv = d4[g];
#pragma unroll
        for (int j = 0; j < 4; j++) {
            int d = (j == 0) ? dv.x : (j == 1) ? dv.y : (j == 2) ? dv.z : dv.w;
            int s = (j == 0) ? sv.x : (j == 1) ? sv.y : (j == 2) ? sv.z : sv.w;
            if ((unsigned)d >= N_NODES) continue;
            int p = rptr[d] + atomicAdd(&cur[d], 1);
            if ((unsigned)p < N_EDGES) {
                esrc[p] = s;
                ewt[p] = ((unsigned)s < N_NODES) ? dinv[s] : 0.f;
            }
        }
    }
}

// aggx = A_norm * x. One node per wave; HALF-WAVE per edge: lanes 0-31 own edge
// 2u, lanes 32-63 edge 2u+1 (float4 lane -> 32x16B = one 512B row per half-wave).
// A batch of 8 slots = 16 edges in flight. Double-buffered idx/wt prefetch
// overlaps the gather vmcnt wait. Padding wt=0. Cross-half __shfl_xor(32) reduce.
__global__ void k_agg_one(const float* __restrict__ xw, const float* __restrict__ dinv,
                          const int* __restrict__ rptr, const int* __restrict__ esrc,
                          const float* __restrict__ ewt, float* __restrict__ outf) {
    int node = blockIdx.x * 4 + (threadIdx.x >> 6);
    int lane = threadIdx.x & 63;
    int epar = lane >> 5;   // edge parity within a slot
    int l32 = lane & 31;    // float4 column
    const float4v* __restrict__ x4 = (const float4v*)xw;  // row = 32 float4
    float dn = dinv[node];
    int e0 = rptr[node], e1 = rptr[node + 1];

    float4v acc;
    if (epar == 0) {
        acc = x4[node * 32 + l32];
        float dn2 = dn * dn;
#pragma unroll
        for (int j = 0; j < 4; j++) acc[j] *= dn2;
    } else {
        acc = (float4v){0.f, 0.f, 0.f, 0.f};
    }

    int idxA[8]; float wtA[8];
#pragma unroll
    for (int u = 0; u < 8; u++) {                    // prologue: batch 0
        int ee = e0 + 2 * u + epar;
        int eec = (ee < N_EDGES) ? ee : (N_EDGES - 1);
        int s = esrc[eec];
        float wv = ewt[eec];
        idxA[u] = ((unsigned)s < N_NODES) ? s : 0;
        wtA[u] = (ee < e1) ? wv : 0.f;
    }

    for (int eb = e0; eb < e1; eb += 16) {
        float4v v[8];
#pragma unroll
        for (int u = 0; u < 8; u++) v[u] = x4[idxA[u] * 32 + l32];   // 16 gathers live
        int nb = eb + 16;
        int pb = (nb < e1) ? nb : eb;                // safe re-read on last batch
        int idxB[8]; float wtB[8];
#pragma unroll
        for (int u = 0; u < 8; u++) {                // prefetch next batch
            int ee = pb + 2 * u + epar;
            int eec = (ee < N_EDGES) ? ee : (N_EDGES - 1);
            int s = esrc[eec];
            float wv = ewt[eec];
            idxB[u] = ((unsigned)s < N_NODES) ? s : 0;
            wtB[u] = (ee < e1) ? wv : 0.f;
        }
#pragma unroll
        for (int u = 0; u < 8; u++) {
            float ww = dn * wtA[u];
#pragma unroll
            for (int j = 0; j < 4; j++) acc[j] += ww * v[u][j];
        }
#pragma unroll
        for (int u = 0; u < 8; u++) { idxA[u] = idxB[u]; wtA[u] = wtB[u]; }
    }

    float4v tot;
#pragma unroll
    for (int j = 0; j < 4; j++) tot[j] = acc[j] + __shfl_xor(acc[j], 32, 64);
    if (epar == 0)
        *(float4v*)(outf + node * 128 + l32 * 4) = tot;
}

// Final aggregate, BOTH branches in one wave: bufi is [node][branch][128], so
// lanes 0-31 (attr) + lanes 32-63 (struct) gather ONE contiguous 1KB block per
// edge. Epilogue: attr half -> out_x fp32 (+b2a); struct half -> hs bf16 (+b2s).
__global__ void k_agg_fin(const float* __restrict__ bufi, const float* __restrict__ dinv,
                          const int* __restrict__ rptr, const int* __restrict__ esrc,
                          const float* __restrict__ ewt,
                          const float* __restrict__ ba, const float* __restrict__ bs,
                          float* __restrict__ out_x, bf16* __restrict__ hs) {
    int node = blockIdx.x * 4 + (threadIdx.x >> 6);
    int lane = threadIdx.x & 63;
    int half = lane >> 5;   // 0 = attr, 1 = struct
    int l32 = lane & 31;    // float4 column within the branch row
    const float4v* __restrict__ b4 = (const float4v*)bufi;  // (node,br) row = 32 float4
    float dn = dinv[node];
    int e0 = rptr[node], e1 = rptr[node + 1];

    float4v acc = b4[(node * 2 + half) * 32 + l32];
    float dn2 = dn * dn;
#pragma unroll
    for (int j = 0; j < 4; j++) acc[j] *= dn2;

    int idxA[8]; float wtA[8];
#pragma unroll
    for (int u = 0; u < 8; u++) {                    // prologue: batch 0 (wave-uniform)
        int ee = e0 + u;
        int eec = (ee < N_EDGES) ? ee : (N_EDGES - 1);
        int s = esrc[eec];
        float wv = ewt[eec];
        idxA[u] = ((unsigned)s < N_NODES) ? s : 0;
        wtA[u] = (ee < e1) ? wv : 0.f;
    }

    for (int eb = e0; eb < e1; eb += 8) {
        float4v v[8];
#pragma unroll
        for (int u = 0; u < 8; u++) v[u] = b4[(idxA[u] * 2 + half) * 32 + l32];
        int nb = eb + 8;
        int pb = (nb < e1) ? nb : eb;
        int idxB[8]; float wtB[8];
#pragma unroll
        for (int u = 0; u < 8; u++) {                // prefetch next batch
            int ee = pb + u;
            int eec = (ee < N_EDGES) ? ee : (N_EDGES - 1);
            int s = esrc[eec];
            float wv = ewt[eec];
            idxB[u] = ((unsigned)s < N_NODES) ? s : 0;
            wtB[u] = (ee < e1) ? wv : 0.f;
        }
#pragma unroll
        for (int u = 0; u < 8; u++) {
            float ww = dn * wtA[u];
#pragma unroll
            for (int j = 0; j < 4; j++) acc[j] += ww * v[u][j];
        }
#pragma unroll
        for (int u = 0; u < 8; u++) { idxA[u] = idxB[u]; wtA[u] = wtB[u]; }
    }

    const float* __restrict__ bias = half ? bs : ba;
    float4v bv = *(const float4v*)(bias + l32 * 4);
#pragma unroll
    for (int j = 0; j < 4; j++) acc[j] += bv[j];

    if (half == 0) {
        *(float4v*)(out_x + node * 128 + l32 * 4) = acc;
    } else {
        ushort4v p;
#pragma unroll
        for (int j = 0; j < 4; j++) {
            bf16 t = __float2bfloat16(acc[j]);
            p[j] = *reinterpret_cast<unsigned short*>(&t);
        }
        *(ushort4v*)((unsigned short*)hs + node * 128 + l32 * 4) = p;
    }
}

// Fused 2-layer MLP per block of 8 nodes, both branches via blockIdx.y:
//   phase1: h1[8][256] = relu(aggx[8 nodes][128] @ W1 + b1)  -> LDS (8 KB)
//   phase2: xw2[8][128] = h1 @ W2  -> bufi[node][br][128] (interleaved)
// LDS reads in phase2 are wave-uniform broadcasts -> conflict-free.
__global__ __launch_bounds__(256) void k_mlp(const float* __restrict__ aggx,
                                             const float* __restrict__ W1a,
                                             const float* __restrict__ W1s,
                                             const float* __restrict__ b1a,
                                             const float* __restrict__ b1s,
                                             const float* __restrict__ W2a,
                                             const float* __restrict__ W2s,
                                             float* __restrict__ bufi) {
    int br = blockIdx.y;
    const float* __restrict__ W1 = br ? W1s : W1a;
    const float* __restrict__ b1 = br ? b1s : b1a;
    const float* __restrict__ W2 = br ? W2s : W2a;

    __shared__ float h1[8][HID_DIM];  // 8 KB
    int t = threadIdx.x;
    int n0 = blockIdx.x * 8;

    // phase 1: t = hidden feature
    {
        float acc[8];
#pragma unroll
        for (int i = 0; i < 8; i++) acc[i] = 0.f;
        const float* __restrict__ Wf = W1 + t;
        const float* __restrict__ x0 = aggx + (size_t)n0 * IN_DIM;
        for (int k = 0; k < IN_DIM; k += 4) {
            float4v xr[8];
#pragma unroll
            for (int i = 0; i < 8; i++)
                xr[i] = *(const float4v*)(x0 + (size_t)i * IN_DIM + k);
#pragma unroll
            for (int kk = 0; kk < 4; kk++) {
                float w = Wf[(size_t)(k + kk) * HID_DIM];
#pragma unroll
                for (int i = 0; i < 8; i++) acc[i] += w * xr[i][kk];
            }
        }
        float b = b1[t];
#pragma unroll
        for (int i = 0; i < 8; i++) h1[i][t] = fmaxf(acc[i] + b, 0.f);
    }
    __syncthreads();

    // phase 2: f = t&127 output feature, half = t>>7 selects nodes 0-3 / 4-7
    {
        int f = t & 127;
        int half = t >> 7;
        float acc[4];
#pragma unroll
        for (int i = 0; i < 4; i++) acc[i] = 0.f;
        const float* __restrict__ Wf = W2 + f;
#pragma unroll 4
        for (int k = 0; k < HID_DIM; k++) {
            float w = Wf[(size_t)k * OUT_DIM];
#pragma unroll
            for (int i = 0; i < 4; i++) acc[i] += w * h1[half * 4 + i][k];
        }
#pragma unroll
        for (int i = 0; i < 4; i++) {
            int n = n0 + half * 4 + i;
            bufi[((size_t)n * 2 + br) * OUT_DIM + f] = acc[i];
        }
    }
}

// S = H * H^T, H: [N_NODES,128] bf16, S: [N_NODES,N_NODES] fp32.
// wave computes a 64x64 block (4x4 tiles of 16x16x32 MFMA); block = 4 waves -> 128x128.
// S is symmetric: store acc[ti][tj] TRANSPOSED so the MFMA reg axis becomes 4
// consecutive COLUMNS of S -> 16 dwordx4 stores/wave covering full 64B lines.
// Nontemporal: the 400 MB S-stream bypasses L2; hs panel stays resident.
__global__ __launch_bounds__(256) void k_sgemm(const bf16* __restrict__ H,
                                               float* __restrict__ S) {
    int w = threadIdx.x >> 6;
    int lane = threadIdx.x & 63;
    int i0 = blockIdx.y * 128 + (w & 1) * 64;
    int j0 = blockIdx.x * 128 + (w >> 1) * 64;
    int l15 = lane & 15;
    int quad = lane >> 4;

    float4v acc[4][4];
    for (int a = 0; a < 4; a++)
        for (int b = 0; b < 4; b++)
            acc[a][b] = (float4v){0.f, 0.f, 0.f, 0.f};

    const short* Hs = (const short*)H;
    for (int kk = 0; kk < 4; kk++) {
        int ko = kk * 32 + quad * 8;
        bshort8 af[4], bfr[4];
#pragma unroll
        for (int t = 0; t < 4; t++) {
            int r = i0 + t * 16 + l15;
            if (r >= N_NODES) r = 0;
            af[t] = *(const bshort8*)(Hs + r * IN_DIM + ko);
            int c = j0 + t * 16 + l15;
            if (c >= N_NODES) c = 0;
            bfr[t] = *(const bshort8*)(Hs + c * IN_DIM + ko);
        }
#pragma unroll
        for (int ti = 0; ti < 4; ti++)
#pragma unroll
            for (int tj = 0; tj < 4; tj++)
                acc[ti][tj] = __builtin_amdgcn_mfma_f32_16x16x32_bf16(
                    af[ti], bfr[tj], acc[ti][tj], 0, 0, 0);
    }

    // transposed (symmetric) store: D[m][n] = S[i0+m][j0+n] = S[j0+n][i0+m]
#pragma unroll
    for (int ti = 0; ti < 4; ti++) {
        int cbase = i0 + ti * 16 + quad * 4;     // 4 consecutive cols (cbase % 4 == 0)
        if (cbase >= N_NODES) continue;          // N % 4 == 0 -> all-or-nothing
#pragma unroll
        for (int tj = 0; tj < 4; tj++) {
            int row = j0 + tj * 16 + l15;
            if (row >= N_NODES) continue;
            __builtin_nontemporal_store(acc[ti][tj],
                                        (float4v*)(S + (size_t)row * N_NODES + cbase));
        }
    }
}

extern "C" void kernel_launch(void* const* d_in, const int* in_sizes, int n_in,
                              void* d_out, int out_size, void* d_ws, size_t ws_size,
                              hipStream_t stream) {
    const float* h   = (const float*)d_in[0];
    const float* W1a = (const float*)d_in[1];
    const float* b1a = (const float*)d_in[2];
    const float* W2a = (const float*)d_in[3];
    const float* b2a = (const float*)d_in[4];
    const float* W1s = (const float*)d_in[5];
    const float* b1s = (const float*)d_in[6];
    const float* W2s = (const float*)d_in[7];
    const float* b2s = (const float*)d_in[8];
    const int* edge  = (const int*)d_in[9];
    const int* src = edge;
    const int* dst = edge + N_EDGES;

    char* ob = (char*)d_out;
    float* aggx = (float*)(ob + SC_AGGX);
    float* bufi = (float*)(ob + SC_BUFI);
    int*   esrc = (int*)(ob + SC_ESRC);
    float* ewt  = (float*)(ob + SC_EWT);
    int*   cnt  = (int*)(ob + SC_CNT);
    int*   cur  = (int*)(ob + SC_CUR);
    int*   rptr = (int*)(ob + SC_RPTR);
    float* dinv = (float*)(ob + SC_DINV);
    bf16*  hs   = (bf16*)(ob + OFF_HS);   // staged in out_h region

    float* out   = (float*)d_out;
    float* out_x = out;                                   // [10000,128]
    float* out_s = out + (size_t)N_NODES * OUT_DIM;       // [10000,10000]
    float* out_h = out_s + (size_t)N_NODES * N_NODES;     // [10000,128]

    // graph prep in ONE cooperative dispatch: zero -> hist -> (dinv+scan) -> fill
    {
        const int* a_src = src; const int* a_dst = dst;
        int* a_cnt = cnt; int* a_cur = cur; int* a_rptr = rptr;
        float* a_dinv = dinv; int* a_esrc = esrc; float* a_ewt = ewt;
        void* args[] = {(void*)&a_src, (void*)&a_dst, (void*)&a_cnt, (void*)&a_cur,
                        (void*)&a_rptr, (void*)&a_dinv, (void*)&a_esrc, (void*)&a_ewt};
        hipLaunchCooperativeKernel((const void*)k_prep, dim3(1024), dim3(256),
                                   args, 0, stream);
    }

    // shared layer-1 aggregation: aggx = A_norm * x (GCN conv is linear:
    // A(xW)+b == (Ax)W+b, and Ax is branch-independent)
    k_agg_one<<<N_NODES / 4, 256, 0, stream>>>(h, dinv, rptr, esrc, ewt, aggx);

    // fused MLP: relu(aggx@W1+b1)@W2 for both branches -> interleaved bufi
    k_mlp<<<dim3(N_NODES / 8, 2), 256, 0, stream>>>(
        aggx, W1a, W1s, b1a, b1s, W2a, W2s, bufi);

    // layer 2 aggregate (both branches per wave) -> out_x (fp32) / hs (bf16)
    k_agg_fin<<<N_NODES / 4, 256, 0, stream>>>(
        bufi, dinv, rptr, esrc, ewt, b2a, b2s, out_x, hs);

    // s_ = h_ @ h_^T  (reads bf16 hs from out_h region, writes fp32 out_s)
    dim3 g((N_NODES + 127) / 128, (N_NODES + 127) / 128);
    k_sgemm<<<g, 256, 0, stream>>>(hs, out_s);

    // third output: h passthrough (overwrites hs staging in out_h)
    hipMemcpyAsync(out_h, h, (size_t)N_NODES * IN_DIM * sizeof(float),
                   hipMemcpyDeviceToDevice, stream);
}